// Round 1
// baseline (930.676 us; speedup 1.0000x reference)
//
#include <hip/hip_runtime.h>
#include <hip/hip_fp16.h>

// Problem constants
constexpr int kB   = 16;    // batch
constexpr int kNum = 2;     // num
constexpr int kInN = 1152;  // in_n
constexpr int kInL = 16;    // in_l
constexpr int kOn  = 64;    // out_n
constexpr int kOl  = 32;    // out_l
constexpr float kEps = 1e-5f;

constexpr int kRow = kOn * kOl;            // 2048 elements per (b,n,i) row
constexpr size_t kUhElems = (size_t)kNum * kInN * kB * kRow;   // 75,497,472 halves
constexpr size_t kUhBytes = kUhElems * 2;                      // 150,994,944 B
constexpr int kAccElems = kB * kNum * kRow;                    // 65,536 floats per small buffer

// i-chunking for routing passes: 1152 = 32 chunks * 36 i; each block = 4 waves,
// wave w handles i = chunk*36 + w, step 4 (9 iters).
constexpr int kChunks = 32;
constexpr int kIPerChunk = 36;

// ---------------------------------------------------------------------------
// Kernel 1: u_hat[n][i][b][o*32+l] (fp16) = sum_k W[n,i,o,l,k]*u[b,n,i,k] + bias[n,o,l]
// Block = (n,i), 512 threads: thread t -> o = t>>3, lg = t&7 (4 l's: lg*4..lg*4+4)
// ---------------------------------------------------------------------------
__global__ __launch_bounds__(512) void k_uhat(const float* __restrict__ u,
                                              const float* __restrict__ W,
                                              const float* __restrict__ bias,
                                              __half* __restrict__ uh) {
  const int blk = blockIdx.x;          // n*kInN + i
  const int n = blk / kInN, i = blk % kInN;
  const int t = threadIdx.x;
  const int o = t >> 3, lg = t & 7;

  __shared__ float4 us4[kB][4];        // u[b][n][i][0:16] as 4x float4
  if (t < kB * 4) {
    const int b = t >> 2, q = t & 3;
    us4[b][q] = *reinterpret_cast<const float4*>(
        &u[(((size_t)b * kNum + n) * kInN + i) * kInL + q * 4]);
  }
  __syncthreads();

  const float* wp = W + ((((size_t)n * kInN + i) * kOn + o) * kOl + lg * 4) * kInL;
  float br[4];
#pragma unroll
  for (int lr = 0; lr < 4; ++lr) br[lr] = bias[(n * kOn + o) * kOl + lg * 4 + lr];

  float uhr[4][kB];
#pragma unroll
  for (int lr = 0; lr < 4; ++lr) {
    float wv[16];
#pragma unroll
    for (int q = 0; q < 4; ++q) {
      float4 f = *reinterpret_cast<const float4*>(wp + lr * kInL + q * 4);
      wv[q * 4 + 0] = f.x; wv[q * 4 + 1] = f.y; wv[q * 4 + 2] = f.z; wv[q * 4 + 3] = f.w;
    }
#pragma unroll
    for (int b = 0; b < kB; ++b) {
      float d = br[lr];
#pragma unroll
      for (int q = 0; q < 4; ++q) {
        float4 uu = us4[b][q];
        d += wv[q * 4 + 0] * uu.x + wv[q * 4 + 1] * uu.y +
             wv[q * 4 + 2] * uu.z + wv[q * 4 + 3] * uu.w;
      }
      uhr[lr][b] = d;
    }
  }

  // row position for this thread's 4 halves: o*32 + lg*4 = t*4
  __half* up = uh + ((size_t)n * kInN + i) * kB * kRow + (size_t)t * 4;
#pragma unroll
  for (int b = 0; b < kB; ++b) {
    __half2 p0 = __floats2half2_rn(uhr[0][b], uhr[1][b]);
    __half2 p1 = __floats2half2_rn(uhr[2][b], uhr[3][b]);
    uint2 pk;
    pk.x = __builtin_bit_cast(unsigned, p0);
    pk.y = __builtin_bit_cast(unsigned, p1);
    *reinterpret_cast<uint2*>(up + (size_t)b * kRow) = pk;
  }
}

// Helper: unpack one 16-byte chunk of 8 halves into hv[idx..idx+8)
__device__ inline void unpack8(uint4 raw, float* hv) {
  const unsigned words[4] = {raw.x, raw.y, raw.z, raw.w};
#pragma unroll
  for (int j = 0; j < 4; ++j) {
    __half2 h = __builtin_bit_cast(__half2, words[j]);
    float2 f = __half22float2(h);
    hv[j * 2 + 0] = f.x;
    hv[j * 2 + 1] = f.y;
  }
}

// Shared epilogue: merge 4 waves' acc[32] via padded LDS, atomicAdd to accum.
__device__ inline void merge_and_flush(float* red, const float acc[kOl], int w,
                                       int lane, int t, int bn,
                                       float* __restrict__ accum) {
#pragma unroll
  for (int l = 0; l < kOl; ++l) red[w * 2112 + lane * 33 + l] = acc[l];
  __syncthreads();
  for (int j = t; j < kRow; j += 256) {
    const int o = j >> 5, l = j & 31;
    const int idx = o * 33 + l;
    float s = red[0 * 2112 + idx] + red[1 * 2112 + idx] +
              red[2 * 2112 + idx] + red[3 * 2112 + idx];
    atomicAdd(&accum[(size_t)bn * kRow + j], s);
  }
}

// ---------------------------------------------------------------------------
// Pass A: v1_pre[b][n][o][l] += sum_i c[i,o] * uh[b,n,i,o,l]
// Block = (chunk, bn); 256 threads = 4 waves, lane = o.
// ---------------------------------------------------------------------------
__global__ __launch_bounds__(256) void k_first(const __half* __restrict__ uh,
                                               const float* __restrict__ c,
                                               float* __restrict__ accum) {
  const int bid = blockIdx.x;
  const int chunk = bid >> 5;
  const int bn = bid & 31;
  const int b = bn >> 1, n = bn & 1;
  const int t = threadIdx.x;
  const int w = t >> 6, lane = t & 63;
  __shared__ float red[4 * 2112];

  float acc[kOl];
#pragma unroll
  for (int l = 0; l < kOl; ++l) acc[l] = 0.f;

  const int i0 = chunk * kIPerChunk;
  for (int i = i0 + w; i < i0 + kIPerChunk; i += 4) {
    const uint4* hp = reinterpret_cast<const uint4*>(
        uh + (((size_t)n * kInN + i) * kB + b) * kRow + lane * kOl);
    float hv[kOl];
#pragma unroll
    for (int q = 0; q < 4; ++q) unpack8(hp[q], &hv[q * 8]);
    const float cio = c[i * kOn + lane];
#pragma unroll
    for (int l = 0; l < kOl; ++l) acc[l] += cio * hv[l];
  }
  merge_and_flush(red, acc, w, lane, t, bn, accum);
}

// ---------------------------------------------------------------------------
// Routing pass: per (b,n,i): s[o] = sum_l uh*v; cc = softmax_o(s); accum += cc*uh
// lane = o; softmax is a pure 64-lane shuffle butterfly (no barriers in loop).
// ---------------------------------------------------------------------------
__global__ __launch_bounds__(256) void k_route(const __half* __restrict__ uh,
                                               const float* __restrict__ vvec,
                                               float* __restrict__ accum) {
  const int bid = blockIdx.x;
  const int chunk = bid >> 5;
  const int bn = bid & 31;
  const int b = bn >> 1, n = bn & 1;
  const int t = threadIdx.x;
  const int w = t >> 6, lane = t & 63;
  __shared__ float red[4 * 2112];

  // v row for this lane's o: v[b][n][lane][0:32]  (32 regs)
  float vr[kOl];
  {
    const float4* vp = reinterpret_cast<const float4*>(
        vvec + (size_t)bn * kRow + lane * kOl);
#pragma unroll
    for (int q = 0; q < 8; ++q) {
      float4 f = vp[q];
      vr[q * 4 + 0] = f.x; vr[q * 4 + 1] = f.y;
      vr[q * 4 + 2] = f.z; vr[q * 4 + 3] = f.w;
    }
  }

  float acc[kOl];
#pragma unroll
  for (int l = 0; l < kOl; ++l) acc[l] = 0.f;

  const int i0 = chunk * kIPerChunk;
  for (int i = i0 + w; i < i0 + kIPerChunk; i += 4) {
    const uint4* hp = reinterpret_cast<const uint4*>(
        uh + (((size_t)n * kInN + i) * kB + b) * kRow + lane * kOl);
    float hv[kOl];
#pragma unroll
    for (int q = 0; q < 4; ++q) unpack8(hp[q], &hv[q * 8]);

    float dot = 0.f;
#pragma unroll
    for (int l = 0; l < kOl; ++l) dot += hv[l] * vr[l];

    // softmax over o (= lanes 0..63)
    float m = dot;
#pragma unroll
    for (int s = 1; s < 64; s <<= 1) m = fmaxf(m, __shfl_xor(m, s));
    const float e = __expf(dot - m);
    float ssum = e;
#pragma unroll
    for (int s = 1; s < 64; s <<= 1) ssum += __shfl_xor(ssum, s);
    const float cc = e / ssum;

#pragma unroll
    for (int l = 0; l < kOl; ++l) acc[l] += cc * hv[l];
  }
  merge_and_flush(red, acc, w, lane, t, bn, accum);
}

// ---------------------------------------------------------------------------
// squash over rows of 32: out = x * s/((1+s)(sqrt(s)+eps)), s = sum(x^2)
// ---------------------------------------------------------------------------
__global__ __launch_bounds__(256) void k_squash(const float* __restrict__ in,
                                                float* __restrict__ out) {
  const int idx = blockIdx.x * 256 + threadIdx.x;
  const float x = in[idx];
  float s = x * x;
#pragma unroll
  for (int d = 1; d < 32; d <<= 1) s += __shfl_xor(s, d, 32);
  const float nrm = sqrtf(s);
  out[idx] = x * (s / ((1.f + s) * (nrm + kEps)));
}

// out = addv + squash(in)   (produces vsum = v1 + v2)
__global__ __launch_bounds__(256) void k_squash_add(const float* __restrict__ in,
                                                    const float* __restrict__ addv,
                                                    float* __restrict__ out) {
  const int idx = blockIdx.x * 256 + threadIdx.x;
  const float x = in[idx];
  float s = x * x;
#pragma unroll
  for (int d = 1; d < 32; d <<= 1) s += __shfl_xor(s, d, 32);
  const float nrm = sqrtf(s);
  out[idx] = addv[idx] + x * (s / ((1.f + s) * (nrm + kEps)));
}

// ---------------------------------------------------------------------------
extern "C" void kernel_launch(void* const* d_in, const int* in_sizes, int n_in,
                              void* d_out, int out_size, void* d_ws, size_t ws_size,
                              hipStream_t stream) {
  const float* u    = (const float*)d_in[0];
  const float* W    = (const float*)d_in[1];
  const float* bias = (const float*)d_in[2];
  const float* c    = (const float*)d_in[3];
  float* out = (float*)d_out;

  char* ws = (char*)d_ws;
  const size_t needed = kUhBytes + 5 * (size_t)kAccElems * 4;
  if (ws_size < needed) return;  // cannot run without scratch

  __half* uh    = (__half*)ws;
  float* v1_pre = (float*)(ws + kUhBytes);
  float* v2_pre = v1_pre + kAccElems;
  float* o_pre  = v2_pre + kAccElems;
  float* v1     = o_pre + kAccElems;
  float* vsum   = v1 + kAccElems;

  // zero the three atomic accumulators (contiguous)
  hipMemsetAsync(v1_pre, 0, (size_t)3 * kAccElems * 4, stream);

  k_uhat<<<kNum * kInN, 512, 0, stream>>>(u, W, bias, uh);
  k_first<<<kChunks * 32, 256, 0, stream>>>(uh, c, v1_pre);
  k_squash<<<kAccElems / 256, 256, 0, stream>>>(v1_pre, v1);
  k_route<<<kChunks * 32, 256, 0, stream>>>(uh, v1, v2_pre);
  k_squash_add<<<kAccElems / 256, 256, 0, stream>>>(v2_pre, v1, vsum);
  k_route<<<kChunks * 32, 256, 0, stream>>>(uh, vsum, o_pre);
  k_squash<<<kAccElems / 256, 256, 0, stream>>>(o_pre, out);
}

// Round 4
// 589.598 us; speedup vs baseline: 1.5785x; 1.5785x over previous
//
#include <hip/hip_runtime.h>
#include <hip/hip_fp16.h>

// Problem constants
constexpr int kB   = 16;    // batch
constexpr int kNum = 2;     // num
constexpr int kInN = 1152;  // in_n
constexpr int kInL = 16;    // in_l
constexpr int kOn  = 64;    // out_n
constexpr int kOl  = 32;    // out_l
constexpr float kEps = 1e-5f;

constexpr int kRow = kOn * kOl;            // 2048 elements per (b,n,i) row
constexpr size_t kUhElems = (size_t)kNum * kInN * kB * kRow;   // 75,497,472 halves
constexpr size_t kUhBytes = kUhElems * 2;                      // 150,994,944 B
constexpr int kAccElems = kB * kNum * kRow;                    // 65,536 floats per small buffer

// i-chunking for routing passes: 1152 = 32 chunks * 36 i; each block = 4 waves,
// wave w handles i = chunk*36 + w, step 4 (9 iters).
constexpr int kChunks = 32;
constexpr int kIPerChunk = 36;

typedef float f32x4 __attribute__((ext_vector_type(4)));

// ---------------------------------------------------------------------------
// Kernel 1: u_hat[n][i][b][o*32+l] (fp16) = sum_k W[n,i,o,l,k]*u[b,n,i,k] + bias[n,o,l]
// Block = (n,i), 512 threads: thread t -> o = t>>3, lg = t&7 (4 l's: lg*4..lg*4+4).
// b is the INNER loop with only 4 live accumulators -> no VGPR spill.
// ---------------------------------------------------------------------------
__global__ __launch_bounds__(512) void k_uhat(const float* __restrict__ u,
                                              const float* __restrict__ W,
                                              const float* __restrict__ bias,
                                              __half* __restrict__ uh) {
  const int blk = blockIdx.x;          // n*kInN + i
  const int n = blk / kInN, i = blk % kInN;
  const int t = threadIdx.x;
  const int o = t >> 3, lg = t & 7;

  __shared__ float us[kB][kInL];       // u[b][n][i][0:16]
  if (t < kB * 4) {
    const int b = t >> 2, q = t & 3;
    const float4 f = *reinterpret_cast<const float4*>(
        &u[(((size_t)b * kNum + n) * kInN + i) * kInL + q * 4]);
    us[b][q * 4 + 0] = f.x; us[b][q * 4 + 1] = f.y;
    us[b][q * 4 + 2] = f.z; us[b][q * 4 + 3] = f.w;
  }
  __syncthreads();

  // Load this thread's 4 rows (l = lg*4..lg*4+3) of W: 64 floats, nontemporal
  // (W is read-once; keep it out of the way of uh in L2/L3).
  const float* wp = W + ((((size_t)n * kInN + i) * kOn + o) * kOl + lg * 4) * kInL;
  float wv[4][kInL];
#pragma unroll
  for (int lr = 0; lr < 4; ++lr) {
#pragma unroll
    for (int q = 0; q < 4; ++q) {
      const f32x4 f = __builtin_nontemporal_load(
          reinterpret_cast<const f32x4*>(wp + lr * kInL + q * 4));
      wv[lr][q * 4 + 0] = f.x; wv[lr][q * 4 + 1] = f.y;
      wv[lr][q * 4 + 2] = f.z; wv[lr][q * 4 + 3] = f.w;
    }
  }
  float br[4];
#pragma unroll
  for (int lr = 0; lr < 4; ++lr) br[lr] = bias[(n * kOn + o) * kOl + lg * 4 + lr];

  // row position for this thread's 4 halves: o*32 + lg*4 = t*4
  __half* up = uh + ((size_t)n * kInN + i) * kB * kRow + (size_t)t * 4;
#pragma unroll
  for (int b = 0; b < kB; ++b) {
    float d0 = br[0], d1 = br[1], d2 = br[2], d3 = br[3];
#pragma unroll
    for (int k = 0; k < kInL; ++k) {
      const float uk = us[b][k];
      d0 += wv[0][k] * uk;
      d1 += wv[1][k] * uk;
      d2 += wv[2][k] * uk;
      d3 += wv[3][k] * uk;
    }
    __half2 p0 = __floats2half2_rn(d0, d1);
    __half2 p1 = __floats2half2_rn(d2, d3);
    uint2 pk;
    pk.x = __builtin_bit_cast(unsigned, p0);
    pk.y = __builtin_bit_cast(unsigned, p1);
    *reinterpret_cast<uint2*>(up + (size_t)b * kRow) = pk;
  }
}

// Helper: unpack one 16-byte chunk of 8 halves into hv[idx..idx+8)
__device__ inline void unpack8(uint4 raw, float* hv) {
  const unsigned words[4] = {raw.x, raw.y, raw.z, raw.w};
#pragma unroll
  for (int j = 0; j < 4; ++j) {
    __half2 h = __builtin_bit_cast(__half2, words[j]);
    float2 f = __half22float2(h);
    hv[j * 2 + 0] = f.x;
    hv[j * 2 + 1] = f.y;
  }
}

// Shared epilogue: merge 4 waves' acc[32] via padded LDS, atomicAdd to accum.
__device__ inline void merge_and_flush(float* red, const float acc[kOl], int w,
                                       int lane, int t, int bn,
                                       float* __restrict__ accum) {
#pragma unroll
  for (int l = 0; l < kOl; ++l) red[w * 2112 + lane * 33 + l] = acc[l];
  __syncthreads();
  for (int j = t; j < kRow; j += 256) {
    const int o = j >> 5, l = j & 31;
    const int idx = o * 33 + l;
    float s = red[0 * 2112 + idx] + red[1 * 2112 + idx] +
              red[2 * 2112 + idx] + red[3 * 2112 + idx];
    atomicAdd(&accum[(size_t)bn * kRow + j], s);
  }
}

// In-register squash of a 32-vector held entirely by one lane.
__device__ inline void squash_inreg(float v[kOl]) {
  float s = 0.f;
#pragma unroll
  for (int l = 0; l < kOl; ++l) s += v[l] * v[l];
  const float nrm = sqrtf(s);
  const float scale = s / ((1.f + s) * (nrm + kEps));
#pragma unroll
  for (int l = 0; l < kOl; ++l) v[l] *= scale;
}

__device__ inline void load_row32(const float* __restrict__ p, float v[kOl]) {
  const float4* vp = reinterpret_cast<const float4*>(p);
#pragma unroll
  for (int q = 0; q < 8; ++q) {
    const float4 f = vp[q];
    v[q * 4 + 0] = f.x; v[q * 4 + 1] = f.y;
    v[q * 4 + 2] = f.z; v[q * 4 + 3] = f.w;
  }
}

// ---------------------------------------------------------------------------
// Pass A: v1_pre[b][n][o][l] += sum_i c[i,o] * uh[b,n,i,o,l]
// Block = (chunk, bn); 256 threads = 4 waves, lane = o.
// ---------------------------------------------------------------------------
__global__ __launch_bounds__(256) void k_first(const __half* __restrict__ uh,
                                               const float* __restrict__ c,
                                               float* __restrict__ accum) {
  const int bid = blockIdx.x;
  const int chunk = bid >> 5;
  const int bn = bid & 31;
  const int b = bn >> 1, n = bn & 1;
  const int t = threadIdx.x;
  const int w = t >> 6, lane = t & 63;
  __shared__ float red[4 * 2112];

  float acc[kOl];
#pragma unroll
  for (int l = 0; l < kOl; ++l) acc[l] = 0.f;

  const int i0 = chunk * kIPerChunk;
  for (int i = i0 + w; i < i0 + kIPerChunk; i += 4) {
    const uint4* hp = reinterpret_cast<const uint4*>(
        uh + (((size_t)n * kInN + i) * kB + b) * kRow + lane * kOl);
    float hv[kOl];
#pragma unroll
    for (int q = 0; q < 4; ++q) unpack8(hp[q], &hv[q * 8]);
    const float cio = c[i * kOn + lane];
#pragma unroll
    for (int l = 0; l < kOl; ++l) acc[l] += cio * hv[l];
  }
  merge_and_flush(red, acc, w, lane, t, bn, accum);
}

// ---------------------------------------------------------------------------
// Routing pass (squash fused): per (b,n):
//   MODE 0: v = squash(pre1 row)
//   MODE 1: v = squash(pre1 row) + squash(pre2 row)
// then per i: s[o] = sum_l uh*v; cc = softmax_o(s); accum += cc*uh
// lane = o; softmax is a pure 64-lane shuffle butterfly (no barriers in loop).
// ---------------------------------------------------------------------------
template <int MODE>
__global__ __launch_bounds__(256) void k_route(const __half* __restrict__ uh,
                                               const float* __restrict__ pre1,
                                               const float* __restrict__ pre2,
                                               float* __restrict__ accum) {
  const int bid = blockIdx.x;
  const int chunk = bid >> 5;
  const int bn = bid & 31;
  const int b = bn >> 1, n = bn & 1;
  const int t = threadIdx.x;
  const int w = t >> 6, lane = t & 63;
  __shared__ float red[4 * 2112];

  // v row for this lane's o, squash(es) computed fully in-register.
  float vr[kOl];
  load_row32(pre1 + (size_t)bn * kRow + lane * kOl, vr);
  squash_inreg(vr);
  if (MODE == 1) {
    float w2[kOl];
    load_row32(pre2 + (size_t)bn * kRow + lane * kOl, w2);
    squash_inreg(w2);
#pragma unroll
    for (int l = 0; l < kOl; ++l) vr[l] += w2[l];
  }

  float acc[kOl];
#pragma unroll
  for (int l = 0; l < kOl; ++l) acc[l] = 0.f;

  const int i0 = chunk * kIPerChunk;
  for (int i = i0 + w; i < i0 + kIPerChunk; i += 4) {
    const uint4* hp = reinterpret_cast<const uint4*>(
        uh + (((size_t)n * kInN + i) * kB + b) * kRow + lane * kOl);
    float hv[kOl];
#pragma unroll
    for (int q = 0; q < 4; ++q) unpack8(hp[q], &hv[q * 8]);

    float dot = 0.f;
#pragma unroll
    for (int l = 0; l < kOl; ++l) dot += hv[l] * vr[l];

    // softmax over o (= lanes 0..63)
    float m = dot;
#pragma unroll
    for (int s = 1; s < 64; s <<= 1) m = fmaxf(m, __shfl_xor(m, s));
    const float e = __expf(dot - m);
    float ssum = e;
#pragma unroll
    for (int s = 1; s < 64; s <<= 1) ssum += __shfl_xor(ssum, s);
    const float cc = e / ssum;

#pragma unroll
    for (int l = 0; l < kOl; ++l) acc[l] += cc * hv[l];
  }
  merge_and_flush(red, acc, w, lane, t, bn, accum);
}

// ---------------------------------------------------------------------------
// Final squash over rows of 32: out = x * s/((1+s)(sqrt(s)+eps)), s = sum(x^2)
// ---------------------------------------------------------------------------
__global__ __launch_bounds__(256) void k_squash(const float* __restrict__ in,
                                                float* __restrict__ out) {
  const int idx = blockIdx.x * 256 + threadIdx.x;
  const float x = in[idx];
  float s = x * x;
#pragma unroll
  for (int d = 1; d < 32; d <<= 1) s += __shfl_xor(s, d, 32);
  const float nrm = sqrtf(s);
  out[idx] = x * (s / ((1.f + s) * (nrm + kEps)));
}

// ---------------------------------------------------------------------------
extern "C" void kernel_launch(void* const* d_in, const int* in_sizes, int n_in,
                              void* d_out, int out_size, void* d_ws, size_t ws_size,
                              hipStream_t stream) {
  const float* u    = (const float*)d_in[0];
  const float* W    = (const float*)d_in[1];
  const float* bias = (const float*)d_in[2];
  const float* c    = (const float*)d_in[3];
  float* out = (float*)d_out;

  char* ws = (char*)d_ws;
  const size_t needed = kUhBytes + 3 * (size_t)kAccElems * 4;
  if (ws_size < needed) return;  // cannot run without scratch

  __half* uh    = (__half*)ws;
  float* v1_pre = (float*)(ws + kUhBytes);
  float* v2_pre = v1_pre + kAccElems;
  float* o_pre  = v2_pre + kAccElems;

  // zero the three atomic accumulators (contiguous)
  hipMemsetAsync(v1_pre, 0, (size_t)3 * kAccElems * 4, stream);

  k_uhat<<<kNum * kInN, 512, 0, stream>>>(u, W, bias, uh);
  k_first<<<kChunks * 32, 256, 0, stream>>>(uh, c, v1_pre);
  k_route<0><<<kChunks * 32, 256, 0, stream>>>(uh, v1_pre, nullptr, v2_pre);
  k_route<1><<<kChunks * 32, 256, 0, stream>>>(uh, v1_pre, v2_pre, o_pre);
  k_squash<<<kAccElems / 256, 256, 0, stream>>>(o_pre, out);
}